// Round 6
// baseline (701.593 us; speedup 1.0000x reference)
//
#include <hip/hip_runtime.h>
#include <hip/hip_bf16.h>
#include <hip/hip_fp16.h>
#include <math.h>

// Problem constants
constexpr int cB   = 2;
constexpr int cS   = 2048;
constexpr int cD   = 1024;
constexpr int cQH  = 16;
constexpr int cKVH = 4;
constexpr int cDH  = 64;
constexpr int cTOPK = 128;
constexpr int cM   = cB * cS;          // 4096 rows for all GEMMs
constexpr int cNB  = cS / 64;          // 32 j-blocks of 64
constexpr int cLSZ = 384;              // kept-list capacity (128 + tie slack)

// Attention tiling (R16): 8 rows / 8 waves / 512 threads per block
constexpr int cTI  = 8;                // query rows per workgroup (= 8 waves)
constexpr int cSTR = 130;              // staging row stride in u32 (128 + pad)

typedef __attribute__((ext_vector_type(8))) short short8;
typedef __attribute__((ext_vector_type(4))) float floatx4;
typedef _Float16 half8 __attribute__((ext_vector_type(8)));

// fp32 -> bf16 round-to-nearest-even (no NaN inputs in this problem)
__device__ inline ushort f2bf(float f) {
    unsigned u = __float_as_uint(f);
    return (ushort)((u + 0x7FFFu + ((u >> 16) & 1u)) >> 16);
}

// ---------------------------------------------------------------------------
// Cast fp32 -> bf16 (raw ushort), n multiple of 4.
// ---------------------------------------------------------------------------
__global__ void cast_f32_bf16(const float* __restrict__ src,
                              ushort* __restrict__ dst, int n) {
    int i4 = (blockIdx.x * blockDim.x + threadIdx.x) * 4;
    if (i4 >= n) return;
    const float4 v = *(const float4*)(src + i4);
    ushort4 r;
    r.x = f2bf(v.x); r.y = f2bf(v.y); r.z = f2bf(v.z); r.w = f2bf(v.w);
    *(ushort4*)(dst + i4) = r;
}

// ---------------------------------------------------------------------------
// MFMA bf16 GEMM: C[m][n] = sum_k A[m][k] * W[n][k]  (A @ W^T), fp32 out.
// 128x128 block tile, BK=32, 256 threads = 4 waves (2x2 of 64x64).
// ---------------------------------------------------------------------------
__global__ __launch_bounds__(256) void gemm_bf16_bt(
        const ushort* __restrict__ A, const ushort* __restrict__ W,
        float* __restrict__ C, int M, int N, int K) {
    __shared__ short As[4][128][8];
    __shared__ short Bs[4][128][8];

    const int tid  = threadIdx.x;
    const int lane = tid & 63;
    const int w    = tid >> 6;          // 0..3
    const int wm   = (w & 1) * 64;
    const int wn   = (w >> 1) * 64;
    const int m0   = blockIdx.y * 128;
    const int n0   = blockIdx.x * 128;

    const int quad = lane >> 4;
    const int l16  = lane & 15;

    floatx4 acc[4][4];
    #pragma unroll
    for (int mi = 0; mi < 4; ++mi)
        #pragma unroll
        for (int ni = 0; ni < 4; ++ni)
            acc[mi][ni] = (floatx4){0.f, 0.f, 0.f, 0.f};

    const int sr = tid >> 1;            // staging row 0..127
    const int sh = (tid & 1) * 2;       // k-chunk pair 0 or 2

    for (int k0 = 0; k0 < K; k0 += 32) {
        const ushort* sa = A + (size_t)(m0 + sr) * K + k0 + sh * 8;
        const short8 a0 = *(const short8*)sa;
        const short8 a1 = *(const short8*)(sa + 8);
        const ushort* sw = W + (size_t)(n0 + sr) * K + k0 + sh * 8;
        const short8 b0 = *(const short8*)sw;
        const short8 b1 = *(const short8*)(sw + 8);
        *(short8*)&As[sh][sr][0]     = a0;
        *(short8*)&As[sh + 1][sr][0] = a1;
        *(short8*)&Bs[sh][sr][0]     = b0;
        *(short8*)&Bs[sh + 1][sr][0] = b1;
        __syncthreads();

        short8 af[4], bf[4];
        #pragma unroll
        for (int mi = 0; mi < 4; ++mi)
            af[mi] = *(const short8*)&As[quad][wm + mi * 16 + l16][0];
        #pragma unroll
        for (int ni = 0; ni < 4; ++ni)
            bf[ni] = *(const short8*)&Bs[quad][wn + ni * 16 + l16][0];
        #pragma unroll
        for (int mi = 0; mi < 4; ++mi)
            #pragma unroll
            for (int ni = 0; ni < 4; ++ni)
                acc[mi][ni] = __builtin_amdgcn_mfma_f32_16x16x32_bf16(
                    af[mi], bf[ni], acc[mi][ni], 0, 0, 0);
        __syncthreads();
    }

    // D layout: col = lane&15, row = quad*4 + reg
    #pragma unroll
    for (int mi = 0; mi < 4; ++mi)
        #pragma unroll
        for (int ni = 0; ni < 4; ++ni)
            #pragma unroll
            for (int r = 0; r < 4; ++r) {
                const int row = m0 + wm + mi * 16 + quad * 4 + r;
                const int col = n0 + wn + ni * 16 + l16;
                C[(size_t)row * N + col] = acc[mi][ni][r];
            }
}

// ---------------------------------------------------------------------------
// Same GEMM, fused RoPE + scale + f16-out epilogue (for Q and K projections).
// Head dim pair (d, d+32) lives in (acc[mi][ni], acc[mi][ni+2]) for ni<2 --
// entirely register-local in the proven D layout.  Same powf/cosf/sinf
// expressions as the old rope_cast_f16 kernel => bit-identical outputs.
// ---------------------------------------------------------------------------
__global__ __launch_bounds__(256) void gemm_bf16_bt_rope_f16(
        const ushort* __restrict__ A, const ushort* __restrict__ W,
        ushort* __restrict__ C, int M, int N, int K, float scale) {
    __shared__ short As[4][128][8];
    __shared__ short Bs[4][128][8];

    const int tid  = threadIdx.x;
    const int lane = tid & 63;
    const int w    = tid >> 6;
    const int wm   = (w & 1) * 64;
    const int wn   = (w >> 1) * 64;
    const int m0   = blockIdx.y * 128;
    const int n0   = blockIdx.x * 128;

    const int quad = lane >> 4;
    const int l16  = lane & 15;

    floatx4 acc[4][4];
    #pragma unroll
    for (int mi = 0; mi < 4; ++mi)
        #pragma unroll
        for (int ni = 0; ni < 4; ++ni)
            acc[mi][ni] = (floatx4){0.f, 0.f, 0.f, 0.f};

    const int sr = tid >> 1;
    const int sh = (tid & 1) * 2;

    for (int k0 = 0; k0 < K; k0 += 32) {
        const ushort* sa = A + (size_t)(m0 + sr) * K + k0 + sh * 8;
        const short8 a0 = *(const short8*)sa;
        const short8 a1 = *(const short8*)(sa + 8);
        const ushort* sw = W + (size_t)(n0 + sr) * K + k0 + sh * 8;
        const short8 b0 = *(const short8*)sw;
        const short8 b1 = *(const short8*)(sw + 8);
        *(short8*)&As[sh][sr][0]     = a0;
        *(short8*)&As[sh + 1][sr][0] = a1;
        *(short8*)&Bs[sh][sr][0]     = b0;
        *(short8*)&Bs[sh + 1][sr][0] = b1;
        __syncthreads();

        short8 af[4], bf[4];
        #pragma unroll
        for (int mi = 0; mi < 4; ++mi)
            af[mi] = *(const short8*)&As[quad][wm + mi * 16 + l16][0];
        #pragma unroll
        for (int ni = 0; ni < 4; ++ni)
            bf[ni] = *(const short8*)&Bs[quad][wn + ni * 16 + l16][0];
        #pragma unroll
        for (int mi = 0; mi < 4; ++mi)
            #pragma unroll
            for (int ni = 0; ni < 4; ++ni)
                acc[mi][ni] = __builtin_amdgcn_mfma_f32_16x16x32_bf16(
                    af[mi], bf[ni], acc[mi][ni], 0, 0, 0);
        __syncthreads();
    }

    // Epilogue: for ni in {0,1}, (colL&63) in [0,32); partner dim at +32 is
    // acc[mi][ni+2].  One powf per ni (lane-invariant across mi,r).
    #pragma unroll
    for (int ni = 0; ni < 2; ++ni) {
        const int colL = n0 + wn + ni * 16 + l16;
        const int d    = colL & 31;
        const float inv_freq = powf(10000.0f, -(float)d / 32.0f);
        #pragma unroll
        for (int mi = 0; mi < 4; ++mi)
            #pragma unroll
            for (int r = 0; r < 4; ++r) {
                const int row = m0 + wm + mi * 16 + quad * 4 + r;
                const int s   = row & (cS - 1);
                const float ang = (float)s * inv_freq;
                const float c   = cosf(ang);
                const float si  = sinf(ang);
                const float x1  = acc[mi][ni][r];
                const float x2  = acc[mi][ni + 2][r];
                const float r1  = (x1 * c - x2 * si) * scale;
                const float r2  = (x2 * c + x1 * si) * scale;
                ushort* o = C + (size_t)row * N + colL;
                o[0]  = __builtin_bit_cast(ushort, (_Float16)r1);
                o[32] = __builtin_bit_cast(ushort, (_Float16)r2);
            }
    }
}

// ---------------------------------------------------------------------------
// Same GEMM, plain f16-out epilogue (for the V projection).
// ---------------------------------------------------------------------------
__global__ __launch_bounds__(256) void gemm_bf16_bt_f16(
        const ushort* __restrict__ A, const ushort* __restrict__ W,
        ushort* __restrict__ C, int M, int N, int K) {
    __shared__ short As[4][128][8];
    __shared__ short Bs[4][128][8];

    const int tid  = threadIdx.x;
    const int lane = tid & 63;
    const int w    = tid >> 6;
    const int wm   = (w & 1) * 64;
    const int wn   = (w >> 1) * 64;
    const int m0   = blockIdx.y * 128;
    const int n0   = blockIdx.x * 128;

    const int quad = lane >> 4;
    const int l16  = lane & 15;

    floatx4 acc[4][4];
    #pragma unroll
    for (int mi = 0; mi < 4; ++mi)
        #pragma unroll
        for (int ni = 0; ni < 4; ++ni)
            acc[mi][ni] = (floatx4){0.f, 0.f, 0.f, 0.f};

    const int sr = tid >> 1;
    const int sh = (tid & 1) * 2;

    for (int k0 = 0; k0 < K; k0 += 32) {
        const ushort* sa = A + (size_t)(m0 + sr) * K + k0 + sh * 8;
        const short8 a0 = *(const short8*)sa;
        const short8 a1 = *(const short8*)(sa + 8);
        const ushort* sw = W + (size_t)(n0 + sr) * K + k0 + sh * 8;
        const short8 b0 = *(const short8*)sw;
        const short8 b1 = *(const short8*)(sw + 8);
        *(short8*)&As[sh][sr][0]     = a0;
        *(short8*)&As[sh + 1][sr][0] = a1;
        *(short8*)&Bs[sh][sr][0]     = b0;
        *(short8*)&Bs[sh + 1][sr][0] = b1;
        __syncthreads();

        short8 af[4], bf[4];
        #pragma unroll
        for (int mi = 0; mi < 4; ++mi)
            af[mi] = *(const short8*)&As[quad][wm + mi * 16 + l16][0];
        #pragma unroll
        for (int ni = 0; ni < 4; ++ni)
            bf[ni] = *(const short8*)&Bs[quad][wn + ni * 16 + l16][0];
        #pragma unroll
        for (int mi = 0; mi < 4; ++mi)
            #pragma unroll
            for (int ni = 0; ni < 4; ++ni)
                acc[mi][ni] = __builtin_amdgcn_mfma_f32_16x16x32_bf16(
                    af[mi], bf[ni], acc[mi][ni], 0, 0, 0);
        __syncthreads();
    }

    #pragma unroll
    for (int mi = 0; mi < 4; ++mi)
        #pragma unroll
        for (int ni = 0; ni < 4; ++ni)
            #pragma unroll
            for (int r = 0; r < 4; ++r) {
                const int row = m0 + wm + mi * 16 + quad * 4 + r;
                const int col = n0 + wn + ni * 16 + l16;
                C[(size_t)row * N + col] =
                    __builtin_bit_cast(ushort, (_Float16)acc[mi][ni][r]);
            }
}

// ---------------------------------------------------------------------------
// Order-preserving float <-> uint bit maps (no NaNs here).
// ---------------------------------------------------------------------------
__device__ inline unsigned fmap(float f) {
    unsigned u = __float_as_uint(f);
    return (u & 0x80000000u) ? ~u : (u | 0x80000000u);
}
__device__ inline float funmap(unsigned u) {
    unsigned v = (u & 0x80000000u) ? (u & 0x7FFFFFFFu) : ~u;
    return __uint_as_float(v);
}

// ---------------------------------------------------------------------------
// MFMA tile attention with exact top-k threshold.  (R17 -> R18 changes)
//
// R17 post-mortem: attn 403us, occ 83%, VALUBusy 62%.  VGPR_Count=32 cannot
// hold key[32] -> compiler parked keys in AGPRs under the 8-wave/64-reg
// budget; every bisection/compaction key access pays an accvgpr move.
// R18:
//  1. amdgpu_waves_per_eu(4,8): allows ~128 regs/wave so key[32] can live in
//     arch VGPRs.  Counter check: VGPR_Count should rise to ~70-100; revert
//     if dur regresses (occupancy loss > inst savings).
//  2. PV uniform-address path: jl[t]/kl[t] are wave-uniform; readfirstlane
//     the v-row offset into an SGPR so loads become SGPR-base + lane offset
//     (addressing rides SALU; saves ~3 VALU/element).  Bit-identical values.
// Everything else identical to R17.
// ---------------------------------------------------------------------------
__global__ __launch_bounds__(512)
__attribute__((amdgpu_waves_per_eu(4, 8)))
void attn_tile_kernel(
        const ushort* __restrict__ qf, const ushort* __restrict__ kf,
        const ushort* __restrict__ vf, ushort* __restrict__ out) {
    extern __shared__ char smem[];
    unsigned* stg = (unsigned*)smem;               // [2][cTI][cSTR] staging
    unsigned* klA = (unsigned*)smem;               // aliases staging (later)
    int*      jlA = (int*)(klA + cTI * cLSZ);

    const int lane = threadIdx.x & 63;
    const int wv   = __builtin_amdgcn_readfirstlane(threadIdx.x >> 6); // 0..7

    // grid: 32 * 256 blocks; it descending so the biggest tiles start first
    const int x  = blockIdx.x;
    const int it = (cS / cTI - 1) - (x >> 5);   // 255..0
    const int bh = x & 31;
    const int h  = bh & 15;
    const int b  = bh >> 4;
    const int kvh = h >> 2;                     // h / (QH/KVH)
    const int i0  = it * cTI;

    const size_t bS = (size_t)b * cS;
    const int l16   = lane & 15;
    const int quad  = lane >> 4;
    const int jperm = ((lane & 3) << 4) + (lane >> 2);   // permuted ownership
    const int i     = i0 + wv;                  // this wave's query row

    // A-frags: q rows i0 + (l16&7) (rows 8..15 duplicate), dims quad*8..+7
    // and +32 (f16, pre-scaled by 1/sqrt(DH))
    const ushort* qp = qf + ((bS + i0 + (l16 & 7)) * cQH + h) * cDH + quad * 8;
    const half8 a0h = __builtin_bit_cast(half8, *(const uint4*)qp);
    const half8 a1h = __builtin_bit_cast(half8, *(const uint4*)(qp + 32));

    unsigned key[cNB];
    #pragma unroll
    for (int jb = 0; jb < cNB; ++jb) key[jb] = 0u;

    const int nk16   = ((i0 + cTI - 1) >> 4) + 1;   // 16-key blocks needed
    const int nchunk = (nk16 + 7) >> 3;             // 128-key chunks

    #pragma unroll
    for (int c = 0; c < 16; ++c) {
        if (c >= nchunk) break;                 // block-uniform branch
        const int  kb16  = (c << 3) + wv;       // this wave's 16-key block
        if (kb16 < nk16) {
            const ushort* kp = kf + ((bS + (kb16 << 4) + l16) * cKVH + kvh) * cDH + quad * 8;
            const uint4 b0 = *(const uint4*)kp;
            const uint4 b1 = *(const uint4*)(kp + 32);
            floatx4 acc = (floatx4){0.f, 0.f, 0.f, 0.f};
            acc = __builtin_amdgcn_mfma_f32_16x16x32_f16(
                a0h, __builtin_bit_cast(half8, b0), acc, 0, 0, 0);
            acc = __builtin_amdgcn_mfma_f32_16x16x32_f16(
                a1h, __builtin_bit_cast(half8, b1), acc, 0, 0, 0);
            // D: row = quad*4 + r2, col = l16.  Rows 8..15 duplicate rows
            // 0..7 -> only quads 0/1 store.  fmap + causal mask folded in.
            if (quad < 2) {
                const int jg = (kb16 << 4) + l16;           // global key idx
                unsigned* sp = stg + (c & 1) * (cTI * cSTR) + (wv << 4) + l16;
                #pragma unroll
                for (int r2 = 0; r2 < 4; ++r2) {
                    const int qrow = quad * 4 + r2;         // 0..7
                    sp[qrow * cSTR] = (jg <= i0 + qrow) ? fmap(acc[r2]) : 0u;
                }
            }
        }
        __syncthreads();
        // gather my row's 128 chunk keys at jperm positions (<=2-way banks)
        {
            const unsigned* rp = stg + (c & 1) * (cTI * cSTR) + wv * cSTR;
            #pragma unroll
            for (int jj = 0; jj < 2; ++jj) {
                const int j = (c << 7) + (jj << 6) + jperm;
                const unsigned kr = rp[(jj << 6) + jperm];
                key[(c << 1) + jj] = (j <= i) ? kr : 0u;
            }
        }
        // double buffer: next chunk stores to the other half; its barrier
        // orders those stores after this chunk's reads.
    }
    __syncthreads();   // staging dead; kl/jl lists may now clobber it

    // ---- Phase 2: per-row exact top-k + softmax + PV (1 row per wave) -----
    const int nb = (i >> 6) + 1;
    unsigned* kl = klA + wv * cLSZ;
    int*      jl = jlA + wv * cLSZ;
    const int vbase0 = (int)(((unsigned)bS * cKVH + kvh) * cDH);

    // row max + min over valid keys (valid keys are never 0)
    unsigned um = 0u, un = 0xFFFFFFFFu;
    #pragma unroll
    for (int jb = 0; jb < cNB; ++jb) {
        if (jb >= nb) break;
        const unsigned kk = key[jb];
        um = max(um, kk);
        un = min(un, kk ? kk : 0xFFFFFFFFu);
    }
    #pragma unroll
    for (int off = 32; off >= 1; off >>= 1) {
        um = max(um, (unsigned)__shfl_xor((int)um, off));
        un = min(un, (unsigned)__shfl_xor((int)un, off));
    }
    const float mrow = funmap(um);

    // exact 128th-largest key.  Bisection in [un, um] with early exit:
    // if count(>=mid) == 128 exactly, threshold = min{key >= mid}.
    // Rows with i < 128 keep everything: ustar = un.
    unsigned ustar;
    if (i < cTOPK) {
        ustar = un;
    } else {
        unsigned lo = un, hi = um;
        while (lo < hi) {
            const unsigned d   = hi - lo;
            const unsigned mid = lo + (d >> 1) + (d & 1u);
            int cnt2 = 0;
            #pragma unroll
            for (int jb = 0; jb < cNB; ++jb) {
                if (jb >= nb) break;
                cnt2 += __popcll(__ballot(key[jb] >= mid));
            }
            if (cnt2 == cTOPK) {
                unsigned mn = 0xFFFFFFFFu;
                #pragma unroll
                for (int jb = 0; jb < cNB; ++jb) {
                    if (jb >= nb) break;
                    const unsigned kk = key[jb];
                    mn = min(mn, (kk >= mid) ? kk : 0xFFFFFFFFu);
                }
                #pragma unroll
                for (int off = 32; off >= 1; off >>= 1)
                    mn = min(mn, (unsigned)__shfl_xor((int)mn, off));
                lo = mn;
                break;
            }
            if (cnt2 > cTOPK) lo = mid; else hi = mid - 1u;
        }
        ustar = lo;
    }

    // ballot-prefix compaction of kept (j, key) into LDS
    const unsigned long long mlt = (1ull << lane) - 1ull;
    int base = 0;
    #pragma unroll
    for (int jb = 0; jb < cNB; ++jb) {
        if (jb >= nb) break;
        const int j = (jb << 6) + jperm;
        const bool keep = (j <= i) && (key[jb] >= ustar);
        const unsigned long long mk = __ballot(keep);
        const int pos = base + __popcll(mk & mlt);
        if (keep && pos < cLSZ) {
            kl[pos] = key[jb];
            jl[pos] = vbase0 + j * (cKVH * cDH);   // v element offset
        }
        base += __popcll(mk);
    }
    const int cnt = min(base, cLSZ);

    // weights + Z
    float zp = 0.f;
    for (int t = lane; t < cnt; t += 64) {
        const float s  = funmap(kl[t]);
        const float wt = __expf(s - mrow);
        ((float*)kl)[t] = wt;
        zp += wt;
    }
    #pragma unroll
    for (int off = 32; off >= 1; off >>= 1) zp += __shfl_xor(zp, off);
    const float invZ = 1.0f / zp;

    // PV: lane = d, f16 v, 8 independent accumulator chains, unroll 2.
    // List entries are wave-uniform: readfirstlane the v-row offset into an
    // SGPR so each load is SGPR-base + lane offset (addressing on SALU).
    float ac0 = 0.f, ac1 = 0.f, ac2 = 0.f, ac3 = 0.f;
    float ac4 = 0.f, ac5 = 0.f, ac6 = 0.f, ac7 = 0.f;
    int t = 0;
    #pragma unroll 2
    for (; t + 7 < cnt; t += 8) {
        const float wt0 = ((float*)kl)[t];
        const float wt1 = ((float*)kl)[t + 1];
        const float wt2 = ((float*)kl)[t + 2];
        const float wt3 = ((float*)kl)[t + 3];
        const float wt4 = ((float*)kl)[t + 4];
        const float wt5 = ((float*)kl)[t + 5];
        const float wt6 = ((float*)kl)[t + 6];
        const float wt7 = ((float*)kl)[t + 7];
        const int so0 = __builtin_amdgcn_readfirstlane(jl[t]);
        const int so1 = __builtin_amdgcn_readfirstlane(jl[t + 1]);
        const int so2 = __builtin_amdgcn_readfirstlane(jl[t + 2]);
        const int so3 = __builtin_amdgcn_readfirstlane(jl[t + 3]);
        const int so4 = __builtin_amdgcn_readfirstlane(jl[t + 4]);
        const int so5 = __builtin_amdgcn_readfirstlane(jl[t + 5]);
        const int so6 = __builtin_amdgcn_readfirstlane(jl[t + 6]);
        const int so7 = __builtin_amdgcn_readfirstlane(jl[t + 7]);
        ac0 += wt0 * (float)__builtin_bit_cast(_Float16, vf[so0 + lane]);
        ac1 += wt1 * (float)__builtin_bit_cast(_Float16, vf[so1 + lane]);
        ac2 += wt2 * (float)__builtin_bit_cast(_Float16, vf[so2 + lane]);
        ac3 += wt3 * (float)__builtin_bit_cast(_Float16, vf[so3 + lane]);
        ac4 += wt4 * (float)__builtin_bit_cast(_Float16, vf[so4 + lane]);
        ac5 += wt5 * (float)__builtin_bit_cast(_Float16, vf[so5 + lane]);
        ac6 += wt6 * (float)__builtin_bit_cast(_Float16, vf[so6 + lane]);
        ac7 += wt7 * (float)__builtin_bit_cast(_Float16, vf[so7 + lane]);
    }
    for (; t < cnt; ++t) {
        const float wt = ((float*)kl)[t];
        const int   so = __builtin_amdgcn_readfirstlane(jl[t]);
        ac0 += wt * (float)__builtin_bit_cast(_Float16, vf[so + lane]);
    }
    const float acc = ((ac0 + ac1) + (ac2 + ac3)) + ((ac4 + ac5) + (ac6 + ac7));
    out[((bS + i) * cQH + h) * cDH + lane] = f2bf(acc * invZ);
}

// ---------------------------------------------------------------------------
// Launch
// ---------------------------------------------------------------------------
extern "C" void kernel_launch(void* const* d_in, const int* in_sizes, int n_in,
                              void* d_out, int out_size, void* d_ws, size_t ws_size,
                              hipStream_t stream) {
    const float* x  = (const float*)d_in[0];
    const float* Wq = (const float*)d_in[1];
    const float* Wk = (const float*)d_in[2];
    const float* Wv = (const float*)d_in[3];
    const float* Wo = (const float*)d_in[4];
    float* out = (float*)d_out;

    // Workspace (all bf16/f16 now; fp32 intermediates eliminated by fused
    // GEMM epilogues): ~33 MB total.
    ushort* xh  = (ushort*)d_ws;                        // 4M bf16
    ushort* Wqh = xh  + (size_t)cM * cD;                // 1M bf16
    ushort* Wkh = Wqh + (size_t)cQH * cDH * cD;         // 256K bf16
    ushort* Wvh = Wkh + (size_t)cKVH * cDH * cD;        // 256K bf16
    ushort* Woh = Wvh + (size_t)cKVH * cDH * cD;        // 1M bf16
    ushort* abh = Woh + (size_t)cD * cQH * cDH;         // 4M bf16 (attn out)
    ushort* qff = abh + (size_t)cM * cQH * cDH;         // 4M f16 (roped q/8)
    ushort* kff = qff + (size_t)cM * cQH * cDH;         // 1M f16 (roped k)
    ushort* vff = kff + (size_t)cM * cKVH * cDH;        // 1M f16

    dim3 blk(256);

    // casts to bf16 (GEMM inputs)
    {
        const int nx  = cM * cD;
        const int nwq = cQH * cDH * cD;
        const int nwk = cKVH * cDH * cD;
        const int nwo = cD * cQH * cDH;
        cast_f32_bf16<<<(nx / 4 + 255) / 256, blk, 0, stream>>>(x, xh, nx);
        cast_f32_bf16<<<(nwq / 4 + 255) / 256, blk, 0, stream>>>(Wq, Wqh, nwq);
        cast_f32_bf16<<<(nwk / 4 + 255) / 256, blk, 0, stream>>>(Wk, Wkh, nwk);
        cast_f32_bf16<<<(nwk / 4 + 255) / 256, blk, 0, stream>>>(Wv, Wvh, nwk);
        cast_f32_bf16<<<(nwo / 4 + 255) / 256, blk, 0, stream>>>(Wo, Woh, nwo);
    }

    // QKV projections with fused RoPE (+1/sqrt(DH) pre-scale for q) / f16 out
    gemm_bf16_bt_rope_f16<<<dim3((cQH * cDH) / 128, cM / 128), blk, 0, stream>>>(
        xh, Wqh, qff, cM, cQH * cDH, cD, 0.125f);
    gemm_bf16_bt_rope_f16<<<dim3((cKVH * cDH) / 128, cM / 128), blk, 0, stream>>>(
        xh, Wkh, kff, cM, cKVH * cDH, cD, 1.0f);
    gemm_bf16_bt_f16<<<dim3((cKVH * cDH) / 128, cM / 128), blk, 0, stream>>>(
        xh, Wvh, vff, cM, cKVH * cDH, cD);

    // Attention: MFMA chunked-transpose kernel, 512 threads, 24 KB LDS
    // (lists 8*384*8 = 24576 B; staging 2*8*130*4 = 8320 B aliases them).
    constexpr size_t aSMEM = (size_t)cTI * cLSZ * 8;    // 24576 B
    static_assert(2 * cTI * cSTR * 4 <= (int)aSMEM, "staging must fit");
    attn_tile_kernel<<<dim3(32 * (cS / cTI)), dim3(512), aSMEM, stream>>>(
        qff, kff, vff, abh);

    // Output projection (bf16 MFMA, fp32 out)
    gemm_bf16_bt<<<dim3(cD / 128, cM / 128), blk, 0, stream>>>(abh, Woh, out, cM, cD, cD);
}

// Round 7
// 531.769 us; speedup vs baseline: 1.3194x; 1.3194x over previous
//
#include <hip/hip_runtime.h>
#include <hip/hip_bf16.h>
#include <hip/hip_fp16.h>
#include <math.h>

// Problem constants
constexpr int cB   = 2;
constexpr int cS   = 2048;
constexpr int cD   = 1024;
constexpr int cQH  = 16;
constexpr int cKVH = 4;
constexpr int cDH  = 64;
constexpr int cTOPK = 128;
constexpr int cM   = cB * cS;          // 4096 rows for all GEMMs
constexpr int cNB  = cS / 64;          // 32 j-blocks of 64
constexpr int cLSZ = 384;              // kept-list capacity (128 + tie slack)

// Attention tiling (R16): 8 rows / 8 waves / 512 threads per block
constexpr int cTI  = 8;                // query rows per workgroup (= 8 waves)
constexpr int cSTR = 130;              // staging row stride in u32 (128 + pad)

// Merged projection sizes
constexpr int cNQ  = cQH * cDH;        // 1024
constexpr int cNK  = cKVH * cDH;       // 256
constexpr int cNQKV = cNQ + 2 * cNK;   // 1536

typedef __attribute__((ext_vector_type(8))) short short8;
typedef __attribute__((ext_vector_type(4))) float floatx4;
typedef _Float16 half8 __attribute__((ext_vector_type(8)));

// fp32 -> bf16 round-to-nearest-even (no NaN inputs in this problem)
__device__ inline ushort f2bf(float f) {
    unsigned u = __float_as_uint(f);
    return (ushort)((u + 0x7FFFu + ((u >> 16) & 1u)) >> 16);
}

// ---------------------------------------------------------------------------
// Merged cast fp32 -> bf16 for all five GEMM inputs.  Destinations are
// contiguous in the workspace (xh|Wqh|Wkh|Wvh|Woh); source picked by region.
// ---------------------------------------------------------------------------
constexpr int cE0 = cM * cD;                 // x end
constexpr int cE1 = cE0 + cNQ * cD;          // Wq end
constexpr int cE2 = cE1 + cNK * cD;          // Wk end
constexpr int cE3 = cE2 + cNK * cD;          // Wv end
constexpr int cE4 = cE3 + cD * cQH * cDH;    // Wo end (= total)

__global__ void cast_all_bf16(const float* __restrict__ x,
                              const float* __restrict__ wq,
                              const float* __restrict__ wk,
                              const float* __restrict__ wv,
                              const float* __restrict__ wo,
                              ushort* __restrict__ dst) {
    const int i4 = (blockIdx.x * blockDim.x + threadIdx.x) * 4;
    if (i4 >= cE4) return;
    const float* s;
    int off;
    if (i4 < cE0)      { s = x;  off = i4; }
    else if (i4 < cE1) { s = wq; off = i4 - cE0; }
    else if (i4 < cE2) { s = wk; off = i4 - cE1; }
    else if (i4 < cE3) { s = wv; off = i4 - cE2; }
    else               { s = wo; off = i4 - cE3; }
    const float4 v = *(const float4*)(s + off);
    ushort4 r;
    r.x = f2bf(v.x); r.y = f2bf(v.y); r.z = f2bf(v.z); r.w = f2bf(v.w);
    *(ushort4*)(dst + i4) = r;
}

// ---------------------------------------------------------------------------
// MFMA bf16 GEMM: C[m][n] = sum_k A[m][k] * W[n][k]  (A @ W^T), fp32 out.
// 128x128 block tile, BK=32, 256 threads = 4 waves (2x2 of 64x64).
// ---------------------------------------------------------------------------
__global__ __launch_bounds__(256) void gemm_bf16_bt(
        const ushort* __restrict__ A, const ushort* __restrict__ W,
        float* __restrict__ C, int M, int N, int K) {
    __shared__ short As[4][128][8];
    __shared__ short Bs[4][128][8];

    const int tid  = threadIdx.x;
    const int lane = tid & 63;
    const int w    = tid >> 6;          // 0..3
    const int wm   = (w & 1) * 64;
    const int wn   = (w >> 1) * 64;
    const int m0   = blockIdx.y * 128;
    const int n0   = blockIdx.x * 128;

    const int quad = lane >> 4;
    const int l16  = lane & 15;

    floatx4 acc[4][4];
    #pragma unroll
    for (int mi = 0; mi < 4; ++mi)
        #pragma unroll
        for (int ni = 0; ni < 4; ++ni)
            acc[mi][ni] = (floatx4){0.f, 0.f, 0.f, 0.f};

    const int sr = tid >> 1;            // staging row 0..127
    const int sh = (tid & 1) * 2;       // k-chunk pair 0 or 2

    for (int k0 = 0; k0 < K; k0 += 32) {
        const ushort* sa = A + (size_t)(m0 + sr) * K + k0 + sh * 8;
        const short8 a0 = *(const short8*)sa;
        const short8 a1 = *(const short8*)(sa + 8);
        const ushort* sw = W + (size_t)(n0 + sr) * K + k0 + sh * 8;
        const short8 b0 = *(const short8*)sw;
        const short8 b1 = *(const short8*)(sw + 8);
        *(short8*)&As[sh][sr][0]     = a0;
        *(short8*)&As[sh + 1][sr][0] = a1;
        *(short8*)&Bs[sh][sr][0]     = b0;
        *(short8*)&Bs[sh + 1][sr][0] = b1;
        __syncthreads();

        short8 af[4], bf[4];
        #pragma unroll
        for (int mi = 0; mi < 4; ++mi)
            af[mi] = *(const short8*)&As[quad][wm + mi * 16 + l16][0];
        #pragma unroll
        for (int ni = 0; ni < 4; ++ni)
            bf[ni] = *(const short8*)&Bs[quad][wn + ni * 16 + l16][0];
        #pragma unroll
        for (int mi = 0; mi < 4; ++mi)
            #pragma unroll
            for (int ni = 0; ni < 4; ++ni)
                acc[mi][ni] = __builtin_amdgcn_mfma_f32_16x16x32_bf16(
                    af[mi], bf[ni], acc[mi][ni], 0, 0, 0);
        __syncthreads();
    }

    // D layout: col = lane&15, row = quad*4 + reg
    #pragma unroll
    for (int mi = 0; mi < 4; ++mi)
        #pragma unroll
        for (int ni = 0; ni < 4; ++ni)
            #pragma unroll
            for (int r = 0; r < 4; ++r) {
                const int row = m0 + wm + mi * 16 + quad * 4 + r;
                const int col = n0 + wn + ni * 16 + l16;
                C[(size_t)row * N + col] = acc[mi][ni][r];
            }
}

// ---------------------------------------------------------------------------
// RoPE + scale + cast to f16, out of place, with source row stride (reads
// from the merged QKV fp32 buffer).  Math identical to the proven kernel.
// dst layout (B*S, H, DH) f16 bits in ushort (packed).
// ---------------------------------------------------------------------------
__global__ void rope_cast_f16(const float* __restrict__ src,
                              ushort* __restrict__ dst, int H, int total,
                              float scale, int srcStride) {
    int idx = blockIdx.x * blockDim.x + threadIdx.x;
    if (idx >= total) return;
    const int d   = idx & 31;
    const int h   = (idx >> 5) % H;
    const int row = idx / (32 * H);
    const int s   = row % cS;
    const float inv_freq = powf(10000.0f, -(float)d / 32.0f);
    const float ang = (float)s * inv_freq;
    const float c  = cosf(ang);
    const float si = sinf(ang);
    const float* p = src + (size_t)row * srcStride + (size_t)h * cDH;
    const float x1 = p[d];
    const float x2 = p[d + 32];
    const float r1 = (x1 * c - x2 * si) * scale;
    const float r2 = (x2 * c + x1 * si) * scale;
    ushort* o = dst + (size_t)row * H * cDH + (size_t)h * cDH;
    o[d]      = __builtin_bit_cast(ushort, (_Float16)r1);
    o[d + 32] = __builtin_bit_cast(ushort, (_Float16)r2);
}

// ---------------------------------------------------------------------------
// Strided fp32 -> f16 cast (V columns of the merged QKV buffer).
// ---------------------------------------------------------------------------
__global__ void cast_f32_f16_strided(const float* __restrict__ src,
                                     ushort* __restrict__ dst,
                                     int total, int cols, int srcStride) {
    const int i4 = (blockIdx.x * blockDim.x + threadIdx.x) * 4;
    if (i4 >= total) return;
    const int row = i4 / cols;          // cols = 256 -> shifts
    const int col = i4 - row * cols;
    const float4 v = *(const float4*)(src + (size_t)row * srcStride + col);
    ushort4 r;
    r.x = __builtin_bit_cast(ushort, (_Float16)v.x);
    r.y = __builtin_bit_cast(ushort, (_Float16)v.y);
    r.z = __builtin_bit_cast(ushort, (_Float16)v.z);
    r.w = __builtin_bit_cast(ushort, (_Float16)v.w);
    *(ushort4*)(dst + i4) = r;
}

// ---------------------------------------------------------------------------
// Order-preserving float <-> uint bit maps (no NaNs here).
// ---------------------------------------------------------------------------
__device__ inline unsigned fmap(float f) {
    unsigned u = __float_as_uint(f);
    return (u & 0x80000000u) ? ~u : (u | 0x80000000u);
}
__device__ inline float funmap(unsigned u) {
    unsigned v = (u & 0x80000000u) ? (u & 0x7FFFFFFFu) : ~u;
    return __uint_as_float(v);
}

// ---------------------------------------------------------------------------
// MFMA tile attention with exact top-k threshold.  (R17 exact — R18's
// waves_per_eu + readfirstlane-PV both regressed and are reverted.)
//
// Structure: 512 threads = 8 waves, cTI=8 query rows, 1 row/wave.
// Phase 1 (chunked MFMA scores -> key[32] registers): per chunk c, wave wv
// computes 16-key block via 2 chained mfma_f32_16x16x32_f16; fmap+causal
// folded into the staging store; double-buffered [2][8][130] staging; wave
// gathers its row's keys at jperm positions (compile-time indices).
// Phase 2: exact early-exit bisection + ballot compaction + softmax + PV.
// Proven constraints: key[32] 1D fully unrolled; no cross-half shuffles on
// the critical chain; permuted key ownership; 8 PV accumulator chains.
// ---------------------------------------------------------------------------
__global__ __launch_bounds__(512) void attn_tile_kernel(
        const ushort* __restrict__ qf, const ushort* __restrict__ kf,
        const ushort* __restrict__ vf, ushort* __restrict__ out) {
    extern __shared__ char smem[];
    unsigned* stg = (unsigned*)smem;               // [2][cTI][cSTR] staging
    unsigned* klA = (unsigned*)smem;               // aliases staging (later)
    int*      jlA = (int*)(klA + cTI * cLSZ);

    const int lane = threadIdx.x & 63;
    const int wv   = __builtin_amdgcn_readfirstlane(threadIdx.x >> 6); // 0..7

    // grid: 32 * 256 blocks; it descending so the biggest tiles start first
    const int x  = blockIdx.x;
    const int it = (cS / cTI - 1) - (x >> 5);   // 255..0
    const int bh = x & 31;
    const int h  = bh & 15;
    const int b  = bh >> 4;
    const int kvh = h >> 2;                     // h / (QH/KVH)
    const int i0  = it * cTI;

    const size_t bS = (size_t)b * cS;
    const int l16   = lane & 15;
    const int quad  = lane >> 4;
    const int jperm = ((lane & 3) << 4) + (lane >> 2);   // permuted ownership
    const int i     = i0 + wv;                  // this wave's query row

    // A-frags: q rows i0 + (l16&7) (rows 8..15 duplicate), dims quad*8..+7
    // and +32 (f16, pre-scaled by 1/sqrt(DH))
    const ushort* qp = qf + ((bS + i0 + (l16 & 7)) * cQH + h) * cDH + quad * 8;
    const half8 a0h = __builtin_bit_cast(half8, *(const uint4*)qp);
    const half8 a1h = __builtin_bit_cast(half8, *(const uint4*)(qp + 32));

    unsigned key[cNB];
    #pragma unroll
    for (int jb = 0; jb < cNB; ++jb) key[jb] = 0u;

    const int nk16   = ((i0 + cTI - 1) >> 4) + 1;   // 16-key blocks needed
    const int nchunk = (nk16 + 7) >> 3;             // 128-key chunks

    #pragma unroll
    for (int c = 0; c < 16; ++c) {
        if (c >= nchunk) break;                 // block-uniform branch
        const int  kb16  = (c << 3) + wv;       // this wave's 16-key block
        if (kb16 < nk16) {
            const ushort* kp = kf + ((bS + (kb16 << 4) + l16) * cKVH + kvh) * cDH + quad * 8;
            const uint4 b0 = *(const uint4*)kp;
            const uint4 b1 = *(const uint4*)(kp + 32);
            floatx4 acc = (floatx4){0.f, 0.f, 0.f, 0.f};
            acc = __builtin_amdgcn_mfma_f32_16x16x32_f16(
                a0h, __builtin_bit_cast(half8, b0), acc, 0, 0, 0);
            acc = __builtin_amdgcn_mfma_f32_16x16x32_f16(
                a1h, __builtin_bit_cast(half8, b1), acc, 0, 0, 0);
            // D: row = quad*4 + r2, col = l16.  Rows 8..15 duplicate rows
            // 0..7 -> only quads 0/1 store.  fmap + causal mask folded in.
            if (quad < 2) {
                const int jg = (kb16 << 4) + l16;           // global key idx
                unsigned* sp = stg + (c & 1) * (cTI * cSTR) + (wv << 4) + l16;
                #pragma unroll
                for (int r2 = 0; r2 < 4; ++r2) {
                    const int qrow = quad * 4 + r2;         // 0..7
                    sp[qrow * cSTR] = (jg <= i0 + qrow) ? fmap(acc[r2]) : 0u;
                }
            }
        }
        __syncthreads();
        // gather my row's 128 chunk keys at jperm positions (<=2-way banks)
        {
            const unsigned* rp = stg + (c & 1) * (cTI * cSTR) + wv * cSTR;
            #pragma unroll
            for (int jj = 0; jj < 2; ++jj) {
                const int j = (c << 7) + (jj << 6) + jperm;
                const unsigned kr = rp[(jj << 6) + jperm];
                key[(c << 1) + jj] = (j <= i) ? kr : 0u;
            }
        }
        // double buffer: next chunk stores to the other half; its barrier
        // orders those stores after this chunk's reads.
    }
    __syncthreads();   // staging dead; kl/jl lists may now clobber it

    // ---- Phase 2: per-row exact top-k + softmax + PV (1 row per wave) -----
    const int nb = (i >> 6) + 1;
    unsigned* kl = klA + wv * cLSZ;
    int*      jl = jlA + wv * cLSZ;
    const int vbase0 = (int)(((unsigned)bS * cKVH + kvh) * cDH);

    // row max + min over valid keys (valid keys are never 0)
    unsigned um = 0u, un = 0xFFFFFFFFu;
    #pragma unroll
    for (int jb = 0; jb < cNB; ++jb) {
        if (jb >= nb) break;
        const unsigned kk = key[jb];
        um = max(um, kk);
        un = min(un, kk ? kk : 0xFFFFFFFFu);
    }
    #pragma unroll
    for (int off = 32; off >= 1; off >>= 1) {
        um = max(um, (unsigned)__shfl_xor((int)um, off));
        un = min(un, (unsigned)__shfl_xor((int)un, off));
    }
    const float mrow = funmap(um);

    // exact 128th-largest key.  Bisection in [un, um] with early exit:
    // if count(>=mid) == 128 exactly, threshold = min{key >= mid}.
    // Rows with i < 128 keep everything: ustar = un.
    unsigned ustar;
    if (i < cTOPK) {
        ustar = un;
    } else {
        unsigned lo = un, hi = um;
        while (lo < hi) {
            const unsigned d   = hi - lo;
            const unsigned mid = lo + (d >> 1) + (d & 1u);
            int cnt2 = 0;
            #pragma unroll
            for (int jb = 0; jb < cNB; ++jb) {
                if (jb >= nb) break;
                cnt2 += __popcll(__ballot(key[jb] >= mid));
            }
            if (cnt2 == cTOPK) {
                unsigned mn = 0xFFFFFFFFu;
                #pragma unroll
                for (int jb = 0; jb < cNB; ++jb) {
                    if (jb >= nb) break;
                    const unsigned kk = key[jb];
                    mn = min(mn, (kk >= mid) ? kk : 0xFFFFFFFFu);
                }
                #pragma unroll
                for (int off = 32; off >= 1; off >>= 1)
                    mn = min(mn, (unsigned)__shfl_xor((int)mn, off));
                lo = mn;
                break;
            }
            if (cnt2 > cTOPK) lo = mid; else hi = mid - 1u;
        }
        ustar = lo;
    }

    // ballot-prefix compaction of kept (j, key) into LDS
    const unsigned long long mlt = (1ull << lane) - 1ull;
    int base = 0;
    #pragma unroll
    for (int jb = 0; jb < cNB; ++jb) {
        if (jb >= nb) break;
        const int j = (jb << 6) + jperm;
        const bool keep = (j <= i) && (key[jb] >= ustar);
        const unsigned long long mk = __ballot(keep);
        const int pos = base + __popcll(mk & mlt);
        if (keep && pos < cLSZ) {
            kl[pos] = key[jb];
            jl[pos] = vbase0 + j * (cKVH * cDH);   // v element offset
        }
        base += __popcll(mk);
    }
    const int cnt = min(base, cLSZ);

    // weights + Z
    float zp = 0.f;
    for (int t = lane; t < cnt; t += 64) {
        const float s  = funmap(kl[t]);
        const float wt = __expf(s - mrow);
        ((float*)kl)[t] = wt;
        zp += wt;
    }
    #pragma unroll
    for (int off = 32; off >= 1; off >>= 1) zp += __shfl_xor(zp, off);
    const float invZ = 1.0f / zp;

    // PV: lane = d, f16 v, 8 independent accumulator chains, unroll 2 so
    // 16 v-loads issue per body (R12-proven load overlap).
    float ac0 = 0.f, ac1 = 0.f, ac2 = 0.f, ac3 = 0.f;
    float ac4 = 0.f, ac5 = 0.f, ac6 = 0.f, ac7 = 0.f;
    int t = 0;
    #pragma unroll 2
    for (; t + 7 < cnt; t += 8) {
        const float wt0 = ((float*)kl)[t];
        const float wt1 = ((float*)kl)[t + 1];
        const float wt2 = ((float*)kl)[t + 2];
        const float wt3 = ((float*)kl)[t + 3];
        const float wt4 = ((float*)kl)[t + 4];
        const float wt5 = ((float*)kl)[t + 5];
        const float wt6 = ((float*)kl)[t + 6];
        const float wt7 = ((float*)kl)[t + 7];
        const int vo0 = jl[t];
        const int vo1 = jl[t + 1];
        const int vo2 = jl[t + 2];
        const int vo3 = jl[t + 3];
        const int vo4 = jl[t + 4];
        const int vo5 = jl[t + 5];
        const int vo6 = jl[t + 6];
        const int vo7 = jl[t + 7];
        ac0 += wt0 * (float)__builtin_bit_cast(_Float16, vf[vo0 + lane]);
        ac1 += wt1 * (float)__builtin_bit_cast(_Float16, vf[vo1 + lane]);
        ac2 += wt2 * (float)__builtin_bit_cast(_Float16, vf[vo2 + lane]);
        ac3 += wt3 * (float)__builtin_bit_cast(_Float16, vf[vo3 + lane]);
        ac4 += wt4 * (float)__builtin_bit_cast(_Float16, vf[vo4 + lane]);
        ac5 += wt5 * (float)__builtin_bit_cast(_Float16, vf[vo5 + lane]);
        ac6 += wt6 * (float)__builtin_bit_cast(_Float16, vf[vo6 + lane]);
        ac7 += wt7 * (float)__builtin_bit_cast(_Float16, vf[vo7 + lane]);
    }
    for (; t < cnt; ++t) {
        const float wt = ((float*)kl)[t];
        const int   vo = jl[t];
        ac0 += wt * (float)__builtin_bit_cast(_Float16, vf[vo + lane]);
    }
    const float acc = ((ac0 + ac1) + (ac2 + ac3)) + ((ac4 + ac5) + (ac6 + ac7));
    out[((bS + i) * cQH + h) * cDH + lane] = f2bf(acc * invZ);
}

// ---------------------------------------------------------------------------
// Launch
// ---------------------------------------------------------------------------
extern "C" void kernel_launch(void* const* d_in, const int* in_sizes, int n_in,
                              void* d_out, int out_size, void* d_ws, size_t ws_size,
                              hipStream_t stream) {
    const float* x  = (const float*)d_in[0];
    const float* Wq = (const float*)d_in[1];
    const float* Wk = (const float*)d_in[2];
    const float* Wv = (const float*)d_in[3];
    const float* Wo = (const float*)d_in[4];
    float* out = (float*)d_out;

    // Workspace:
    //   qkvb : merged QKV projection output, fp32 (4096 x 1536) = 25.2 MB
    //   bf16 inputs (contiguous, single merged cast): xh|Wqh|Wkh|Wvh|Woh
    //   abh  : attention out (bf16), qff/kff (roped f16), vff (f16)
    float*  qkvb = (float*)d_ws;                        // 6.29M f32
    ushort* xh   = (ushort*)(qkvb + (size_t)cM * cNQKV);
    ushort* Wqh  = xh  + (size_t)cM * cD;               // 1024 rows x 1024
    ushort* Wkh  = Wqh + (size_t)cNQ * cD;              // 256 rows
    ushort* Wvh  = Wkh + (size_t)cNK * cD;              // 256 rows (contig!)
    ushort* Woh  = Wvh + (size_t)cNK * cD;              // 1024 rows
    ushort* abh  = Woh + (size_t)cD * cQH * cDH;        // 4M bf16 (attn out)
    ushort* qff  = abh + (size_t)cM * cQH * cDH;        // 4M f16 (roped q/8)
    ushort* kff  = qff + (size_t)cM * cQH * cDH;        // 1M f16 (roped k)
    ushort* vff  = kff + (size_t)cM * cKVH * cDH;       // 1M f16

    dim3 blk(256);

    // one merged cast for all five bf16 GEMM inputs (dst contiguous)
    cast_all_bf16<<<(cE4 / 4 + 255) / 256, blk, 0, stream>>>(
        x, Wq, Wk, Wv, Wo, xh);

    // ONE merged QKV projection: W = [Wq; Wk; Wv] rows (contiguous bf16),
    // C = qkvb (4096 x 1536 fp32).  Bit-identical per-column results vs
    // separate GEMMs (same K-loop / MFMA sequence).
    gemm_bf16_bt<<<dim3(cNQKV / 128, cM / 128), blk, 0, stream>>>(
        xh, Wqh, qkvb, cM, cNQKV, cD);

    // Fused RoPE + cast to f16 (q pre-scaled by 1/sqrt(DH)); v cast to f16.
    {
        const int totq = cM * cQH * 32;
        const int totk = cM * cKVH * 32;
        rope_cast_f16<<<(totq + 255) / 256, blk, 0, stream>>>(
            qkvb, qff, cQH, totq, 0.125f, cNQKV);
        rope_cast_f16<<<(totk + 255) / 256, blk, 0, stream>>>(
            qkvb + cNQ, kff, cKVH, totk, 1.0f, cNQKV);
        const int nv = cM * cNK;
        cast_f32_f16_strided<<<(nv / 4 + 255) / 256, blk, 0, stream>>>(
            qkvb + cNQ + cNK, vff, nv, cNK, cNQKV);
    }

    // Attention: MFMA chunked-transpose kernel, 512 threads, 24 KB LDS
    // (lists 8*384*8 = 24576 B; staging 2*8*130*4 = 8320 B aliases them).
    constexpr size_t aSMEM = (size_t)cTI * cLSZ * 8;    // 24576 B
    static_assert(2 * cTI * cSTR * 4 <= (int)aSMEM, "staging must fit");
    attn_tile_kernel<<<dim3(32 * (cS / cTI)), dim3(512), aSMEM, stream>>>(
        qff, kff, vff, abh);

    // Output projection (bf16 MFMA, fp32 out)
    gemm_bf16_bt<<<dim3(cD / 128, cM / 128), blk, 0, stream>>>(abh, Woh, out, cM, cD, cD);
}